// Round 10
// baseline (978.596 us; speedup 1.0000x reference)
//
#include <hip/hip_runtime.h>
#include <math.h>

#define N_ATOMS 2048
#define NM      512
#define KHALF   9040          // half k-grid (k=0 excluded; pairs folded into wk^2=2*kfac)
#define KPAD    9216          // padded, wk=0 on pads
#define TWO_PI  6.2831853071795864769f
#define SIGMA   0.5540037f
#define FOUR_PI 12.566370614359172954f

__device__ inline void inv3x3(const float* __restrict__ c, float inv[3][3], float& det) {
    float a00=c[0],a01=c[1],a02=c[2],a10=c[3],a11=c[4],a12=c[5],a20=c[6],a21=c[7],a22=c[8];
    float c00 =  a11*a22 - a12*a21;
    float c01 = -(a10*a22 - a12*a20);
    float c02 =  a10*a21 - a11*a20;
    det = a00*c00 + a01*c01 + a02*c02;
    float id = 1.0f/det;
    inv[0][0] = c00*id;
    inv[0][1] = -(a01*a22 - a02*a21)*id;
    inv[0][2] =  (a01*a12 - a02*a11)*id;
    inv[1][0] = c01*id;
    inv[1][1] =  (a00*a22 - a02*a20)*id;
    inv[1][2] = -(a00*a12 - a02*a10)*id;
    inv[2][0] = c02*id;
    inv[2][1] = -(a00*a21 - a01*a20)*id;
    inv[2][2] =  (a00*a11 - a01*a10)*id;
}

// ---------------- kernel 1: k-grid + atom prep ----------------
__global__ void prep(const float* __restrict__ pos, const float* __restrict__ qv,
                     const float* __restrict__ cell, float4* __restrict__ kdata,
                     float4* __restrict__ uq, float* __restrict__ out) {
    const int bb = blockIdx.x, tid = threadIdx.x;
    if (bb < 36) {
        int t = bb*256 + tid;
        float gx=0.f, gy=0.f, gz=0.f, wk=0.f;
        if (t < KHALF) {
            int iz = t % 41; int rem = t / 41; int iy = rem % 21; int ix = rem / 21;
            gx = (float)(ix - 10); gy = (float)(iy - 10); gz = (float)(iz - 20);
            float inv[3][3], det;
            inv3x3(cell, inv, det);
            float kx = TWO_PI*(gx*inv[0][0] + gy*inv[0][1] + gz*inv[0][2]);
            float ky = TWO_PI*(gx*inv[1][0] + gy*inv[1][1] + gz*inv[1][2]);
            float kz = TWO_PI*(gx*inv[2][0] + gy*inv[2][1] + gz*inv[2][2]);
            float k2 = kx*kx + ky*ky + kz*kz;
            float kfac = __expf(-0.5f*SIGMA*SIGMA*k2) / k2;
            wk = sqrtf(2.0f*kfac);
        }
        kdata[t] = make_float4(gx, gy, gz, wk);
    } else {
        int i = (bb-36)*256 + tid;
        float inv[3][3], det;
        inv3x3(cell, inv, det);
        float x = pos[3*i], y = pos[3*i+1], z = pos[3*i+2];
        float u = x*inv[0][0] + y*inv[1][0] + z*inv[2][0];
        float v = x*inv[0][1] + y*inv[1][1] + z*inv[2][1];
        float w = x*inv[0][2] + y*inv[1][2] + z*inv[2][2];
        float qi = qv[i];
        uq[i] = make_float4(u, v, w, qi);
        if (i >= NM) out[i] = qi;
        if (i == 0) { out[N_ATOMS] = 0.f; out[N_ATOMS+1] = 0.f; }
    }
}

// ---------------- kernel 2: split-K SYRK + structf (folded) ----------------
__global__ void __launch_bounds__(256, 2) syrk_sf(const float4* __restrict__ kdata,
        const float4* __restrict__ uq, float* __restrict__ partial,
        float* __restrict__ Scw, float* __restrict__ Ssw, int SL, int KSL, int nsyrk) {
    __shared__ float smem[16384];
    const int tid = threadIdx.x;
    if ((int)blockIdx.x >= nsyrk) {
        int ch = blockIdx.x - nsyrk;          // 0..143
        int kk = tid & 63, sp = tid >> 6;
        int k = ch*64 + kk;
        float4 kd = kdata[k];
        float sc = 0.f, ss = 0.f;
        int jlo = NM + sp*384, jhi = jlo + 384;
        for (int j = jlo; j < jhi; ++j) {
            float4 at = uq[j];
            float ph = TWO_PI*(kd.x*at.x + kd.y*at.y + kd.z*at.z);
            float s, c; __sincosf(ph, &s, &c);
            sc += at.w * c;
            ss += at.w * s;
        }
        smem[sp*64 + kk] = sc;
        smem[256 + sp*64 + kk] = ss;
        __syncthreads();
        if (sp == 0) {
            float c = smem[kk] + smem[64+kk] + smem[128+kk] + smem[192+kk];
            float s = smem[256+kk] + smem[320+kk] + smem[384+kk] + smem[448+kk];
            float kf2 = kd.w * kd.w;
            Scw[k] = kf2 * c;
            Ssw[k] = kf2 * s;
        }
        return;
    }
    int s = blockIdx.x % SL;
    int t = blockIdx.x / SL;
    int rt = 0;
    while ((rt+1)*(rt+2)/2 <= t) ++rt;
    int ct = t - rt*(rt+1)/2;
    const int row0 = rt << 7, c0 = ct << 7;
    const bool diag = (row0 == c0);
    float* crT = smem; float* srT = smem+4096; float* ccT = smem+8192; float* scT = smem+12288;
    const float* ccR = diag ? crT : ccT;   // diagonal tiles: col phases == row phases
    const float* scR = diag ? srT : scT;
    const int i0 = (tid & 15) << 3;
    const int j0 = (tid >> 4) << 3;
    float acc[8][8];
    #pragma unroll
    for (int i = 0; i < 8; ++i)
        #pragma unroll
        for (int j = 0; j < 8; ++j) acc[i][j] = 0.f;
    const int k0 = s * KSL;
    const int nch = KSL >> 5;
    for (int ch = 0; ch < nch; ++ch) {
        int kc = k0 + (ch << 5);
        __syncthreads();
        #pragma unroll
        for (int w = 0; w < 16; ++w) {
            int job = tid + (w << 8);
            int kk = job >> 7, a = job & 127;
            float4 kd = kdata[kc + kk];
            float4 at = uq[row0 + a];
            float ph = TWO_PI*(kd.x*at.x + kd.y*at.y + kd.z*at.z);
            float sn, cs;
            __sincosf(ph, &sn, &cs);
            crT[kk*128+a] = kd.w * cs;
            srT[kk*128+a] = kd.w * sn;
        }
        if (!diag) {
            #pragma unroll
            for (int w = 0; w < 16; ++w) {
                int job = tid + (w << 8);
                int kk = job >> 7, a = job & 127;
                float4 kd = kdata[kc + kk];
                float4 at = uq[c0 + a];
                float ph = TWO_PI*(kd.x*at.x + kd.y*at.y + kd.z*at.z);
                float sn, cs;
                __sincosf(ph, &sn, &cs);
                ccT[kk*128+a] = kd.w * cs;
                scT[kk*128+a] = kd.w * sn;
            }
        }
        __syncthreads();
        #pragma unroll 4
        for (int kk = 0; kk < 32; ++kk) {
            float cr[8], sr[8], cc[8], sv[8];
            *(float4*)&cr[0] = *(const float4*)&crT[kk*128+i0];
            *(float4*)&cr[4] = *(const float4*)&crT[kk*128+i0+4];
            *(float4*)&sr[0] = *(const float4*)&srT[kk*128+i0];
            *(float4*)&sr[4] = *(const float4*)&srT[kk*128+i0+4];
            *(float4*)&cc[0] = *(const float4*)&ccR[kk*128+j0];
            *(float4*)&cc[4] = *(const float4*)&ccR[kk*128+j0+4];
            *(float4*)&sv[0] = *(const float4*)&scR[kk*128+j0];
            *(float4*)&sv[4] = *(const float4*)&scR[kk*128+j0+4];
            #pragma unroll
            for (int i = 0; i < 8; ++i)
                #pragma unroll
                for (int j = 0; j < 8; ++j)
                    acc[i][j] += cr[i]*cc[j] + sr[i]*sv[j];
        }
    }
    float* P = partial + ((size_t)blockIdx.x << 14);
    #pragma unroll
    for (int i = 0; i < 8; ++i) {
        *(float4*)&P[(i0+i)*128 + j0]     = make_float4(acc[i][0], acc[i][1], acc[i][2], acc[i][3]);
        *(float4*)&P[(i0+i)*128 + j0 + 4] = make_float4(acc[i][4], acc[i][5], acc[i][6], acc[i][7]);
    }
}

// ---------------- kernel 3: reduceA + field ----------------
__global__ void __launch_bounds__(256) redfield(const float* __restrict__ partial,
        const float* __restrict__ cell, float* __restrict__ Amat,
        const float4* __restrict__ kdata, const float4* __restrict__ uq,
        const float* __restrict__ Scw, const float* __restrict__ Ssw,
        float* __restrict__ Bvec, int SL) {
    const int b = blockIdx.x, tid = threadIdx.x;
    float inv[3][3], det;
    inv3x3(cell, inv, det);
    const float scal = FOUR_PI / fabsf(det);
    if (b < 512) {
        for (int idx = b*256 + tid; idx < 512*512; idx += 512*256) {
            int i = idx >> 9, j = idx & 511;
            if (i < j) continue;
            int rt2 = i >> 7, ct2 = j >> 7;
            int t2 = rt2*(rt2+1)/2 + ct2;
            const float* p = partial + ((size_t)(t2*SL) << 14) + ((i & 127) << 7) + (j & 127);
            float a0=0.f,a1=0.f,a2=0.f,a3=0.f,a4=0.f,a5=0.f,a6=0.f,a7=0.f;
            int s = 0;
            for (; s + 8 <= SL; s += 8) {
                a0 += p[(size_t)(s+0) << 14];
                a1 += p[(size_t)(s+1) << 14];
                a2 += p[(size_t)(s+2) << 14];
                a3 += p[(size_t)(s+3) << 14];
                a4 += p[(size_t)(s+4) << 14];
                a5 += p[(size_t)(s+5) << 14];
                a6 += p[(size_t)(s+6) << 14];
                a7 += p[(size_t)(s+7) << 14];
            }
            for (; s < SL; ++s) a0 += p[(size_t)s << 14];
            float sum = ((a0+a1)+(a2+a3)) + ((a4+a5)+(a6+a7));
            float v = scal * sum;
            Amat[(size_t)i*512 + j] = v;
            Amat[(size_t)j*512 + i] = v;
        }
    } else {
        int ch = b - 512;
        int atom = ch*4 + (tid >> 6);
        int lane = tid & 63;
        float4 at = uq[atom];
        float acc = 0.f;
        for (int k = lane; k < KPAD; k += 64) {
            float4 kd = kdata[k];
            float ph = TWO_PI*(kd.x*at.x + kd.y*at.y + kd.z*at.z);
            float s, c; __sincosf(ph, &s, &c);
            acc += c*Scw[k] + s*Ssw[k];
        }
        #pragma unroll
        for (int off = 32; off; off >>= 1) acc += __shfl_down(acc, off);
        if (lane == 0) Bvec[atom] = -scal * acc;
    }
}

// ---- pivot factor+inverse (512 threads): stage A[p][p], register-wave chol,
//      T = L^{-1} via doubling; writes TT (ld64 transposed) + Dinvs[p] ----
__device__ void pivot_factor(float* smem, float* TT, int tid, int p,
                             float* Amat, float* Dinvs) {
    float* D = smem + 4352;    // [64][68]
    float* T = smem + 8704;    // [64][68]
    float* M = smem + 13056;   // [1024]
    for (int idx = tid; idx < 4096; idx += 512) {
        int r = idx >> 6, c = idx & 63;
        D[r*68+c] = Amat[(size_t)(p*64+r)*512 + p*64 + c];
    }
    __syncthreads();
    if (tid < 64) {
        float row[64];
        #pragma unroll
        for (int c = 0; c < 64; ++c) row[c] = D[tid*68 + c];
        #pragma unroll
        for (int j = 0; j < 64; ++j) {
            float pj = __shfl(row[j], j);
            float rinv = 1.0f / sqrtf(pj);
            float lj = row[j] * rinv;
            row[j] = lj;
            #pragma unroll
            for (int c = j+1; c < 64; ++c) {
                float lcj = __shfl(lj, c);
                row[c] = fmaf(-lj, lcj, row[c]);
            }
        }
        #pragma unroll
        for (int c = 0; c < 64; ++c) D[tid*68 + c] = row[c];
    }
    __syncthreads();
    for (int idx = tid; idx < 64*68; idx += 512) T[idx] = 0.f;
    __syncthreads();
    if (tid < 64) {
        int s = tid >> 3, c = tid & 7, o = s*8;
        float x[8];
        #pragma unroll
        for (int r = 0; r < 8; ++r) {
            float acc = (r == c) ? 1.0f : 0.0f;
            #pragma unroll
            for (int j = 0; j < 8; ++j)
                if (j < r) acc -= D[(o+r)*68 + o + j] * x[j];
            x[r] = (r >= c) ? acc / D[(o+r)*68 + o + r] : 0.0f;
        }
        #pragma unroll
        for (int r = 0; r < 8; ++r)
            if (r >= c) T[(o+r)*68 + o + c] = x[r];
    }
    __syncthreads();
    #pragma unroll
    for (int lvl = 0; lvl < 3; ++lvl) {
        int h = 8 << lvl, pairs = 4 >> lvl, hh = h*h;
        for (int e = tid; e < pairs*hh; e += 512) {   // M = L21 * W11
            int pr = e / hh, rem = e - pr*hh, r2 = rem / h, c2 = rem - (rem/h)*h;
            int o = pr*2*h;
            float acc = 0.f;
            for (int j2 = c2; j2 < h; ++j2)
                acc += D[(o+h+r2)*68 + o + j2] * T[(o+j2)*68 + o + c2];
            M[e] = acc;
        }
        __syncthreads();
        for (int e = tid; e < pairs*hh; e += 512) {   // W21 = -W22 * M
            int pr = e / hh, rem = e - pr*hh, r2 = rem / h, c2 = rem - (rem/h)*h;
            int o = pr*2*h;
            float acc = 0.f;
            for (int j2 = 0; j2 <= r2; ++j2)
                acc += T[(o+h+r2)*68 + o+h + j2] * M[pr*hh + j2*h + c2];
            T[(o+h+r2)*68 + o + c2] = -acc;
        }
        __syncthreads();
    }
    for (int idx = tid; idx < 4096; idx += 512) {
        int r = idx >> 6, c = idx & 63;
        float v = (c <= r) ? T[r*68+c] : 0.f;
        TT[c*64 + r] = v;                 // TT[k][c] = Dinv[c][k]
        Dinvs[p*4096 + idx] = v;
    }
    __syncthreads();
}

// ---------------- kernel 4: ONE-BLOCK Cholesky + 2-RHS solve + combine ----------------
__global__ void __launch_bounds__(512) chol_solve(float* __restrict__ Amat,
        float* __restrict__ LmatT, float* __restrict__ Dinvs,
        const float* __restrict__ Bvec, float* __restrict__ out) {
    __shared__ float smem[14080];   // TT[0,4096) | slotA@4352 | slotB@8704 | M@13056
    float* TT = smem;               // [64][64]: TT[k][c] = Dinv[c][k]
    const int tid = threadIdx.x;
    const int i0 = (tid & 15)*4, q0 = (tid >> 4)*2;   // 64x64 cover, 4x2 per thread

    for (int p = 0; p < 8; ++p) {
        pivot_factor(smem, TT, tid, p, Amat, Dinvs);
        float* ArS = smem + 4352;   // [64][68]  (aliases D; later aliases LcS)
        float* LrS = smem + 8704;   // [64][68]  (aliases T)
        float* LcS = smem + 4352;
        for (int R = p+1; R < 8; ++R) {
            __syncthreads();   // previous C-loop finished reading LcS/LrS
            for (int idx = tid; idx < 4096; idx += 512) {
                int i = idx >> 6, k = idx & 63;
                ArS[k*68 + i] = Amat[(size_t)(R*64+i)*512 + p*64 + k];
            }
            __syncthreads();
            // Lr[i][c] = sum_k ArS[k][i] * TT[k][c]
            float lr[4][2];
            #pragma unroll
            for (int ii = 0; ii < 4; ++ii) { lr[ii][0] = 0.f; lr[ii][1] = 0.f; }
            for (int k = 0; k < 64; ++k) {
                float4 av = *(float4*)&ArS[k*68 + i0];
                float2 dv = *(float2*)&TT[k*64 + q0];
                lr[0][0] += av.x*dv.x; lr[0][1] += av.x*dv.y;
                lr[1][0] += av.y*dv.x; lr[1][1] += av.y*dv.y;
                lr[2][0] += av.z*dv.x; lr[2][1] += av.z*dv.y;
                lr[3][0] += av.w*dv.x; lr[3][1] += av.w*dv.y;
            }
            __syncthreads();   // done reading ArS (slotA free for LcS)
            #pragma unroll
            for (int ii = 0; ii < 4; ++ii) {
                LrS[(q0+0)*68 + i0+ii] = lr[ii][0];
                LrS[(q0+1)*68 + i0+ii] = lr[ii][1];
            }
            __syncthreads();
            // write L panel into Amat (in place) + LmatT
            for (int idx = tid; idx < 4096; idx += 512) {
                int i2 = idx >> 6, c2 = idx & 63;
                Amat[(size_t)(R*64+i2)*512 + p*64 + c2] = LrS[c2*68 + i2];
            }
            for (int idx = tid; idx < 4096; idx += 512) {
                int c2 = idx >> 6, i2 = idx & 63;
                LmatT[(size_t)(p*64+c2)*512 + R*64 + i2] = LrS[c2*68 + i2];
            }
            // trailing updates: C = p+1 .. R (C==R last uses LrS directly)
            for (int C = p+1; C <= R; ++C) {
                const float* Lc;
                if (C == R) {
                    Lc = LrS;
                } else {
                    __syncthreads();   // prior SYRK finished reading LcS
                    for (int idx = tid; idx < 4096; idx += 512) {
                        int j2 = idx >> 6, c2 = idx & 63;
                        LcS[c2*68 + j2] = Amat[(size_t)(C*64+j2)*512 + p*64 + c2];
                    }
                    __syncthreads();
                    Lc = LcS;
                }
                float up[4][2];
                #pragma unroll
                for (int ii = 0; ii < 4; ++ii) { up[ii][0] = 0.f; up[ii][1] = 0.f; }
                for (int c2 = 0; c2 < 64; ++c2) {
                    float4 lv = *(float4*)&LrS[c2*68 + i0];
                    float2 cv = *(float2*)&Lc[c2*68 + q0];
                    up[0][0] += lv.x*cv.x; up[0][1] += lv.x*cv.y;
                    up[1][0] += lv.y*cv.x; up[1][1] += lv.y*cv.y;
                    up[2][0] += lv.z*cv.x; up[2][1] += lv.z*cv.y;
                    up[3][0] += lv.w*cv.x; up[3][1] += lv.w*cv.y;
                }
                #pragma unroll
                for (int ii = 0; ii < 4; ++ii) {
                    size_t g0 = (size_t)(R*64+i0+ii)*512 + C*64 + q0;
                    Amat[g0]     -= up[ii][0];
                    Amat[g0 + 1] -= up[ii][1];
                }
            }
            __threadfence();   // publish RMWs + L panel (same-CU L1 safety)
            __syncthreads();
        }
    }

    // ---- solve: L z = [B,1]; L^T x = z; combine; out[0:512] ----
    {
        float* rb  = smem + 4352;
        float* ro  = smem + 4864;
        float* xb  = smem + 5376;
        float* xo  = smem + 5888;
        float* bvs = smem + 6400;
        float* red = smem + 6912;
        __threadfence();
        __syncthreads();
        for (int i = tid; i < 512; i += 512) {
            float bv = Bvec[i];
            bvs[i] = bv; rb[i] = bv; ro[i] = 1.0f;
        }
        __syncthreads();
        for (int k = 0; k < 8; ++k) {          // forward
            if (tid < 64) {
                const float* Dk = Dinvs + k*4096 + tid*64;
                float s1 = 0.f, s2 = 0.f;
                for (int c4 = 0; c4 < 16; ++c4) {
                    float4 w = *(const float4*)&Dk[c4*4];
                    int cb = 64*k + c4*4;
                    s1 += w.x*rb[cb] + w.y*rb[cb+1] + w.z*rb[cb+2] + w.w*rb[cb+3];
                    s2 += w.x*ro[cb] + w.y*ro[cb+1] + w.z*ro[cb+2] + w.w*ro[cb+3];
                }
                rb[64*k+tid] = s1; ro[64*k+tid] = s2;   // wave-lockstep
            }
            __syncthreads();
            for (int mm = 64*(k+1) + tid; mm < 512; mm += 512) {
                const float* Lr = Amat + (size_t)mm*512 + 64*k;
                float s1 = 0.f, s2 = 0.f;
                for (int c4 = 0; c4 < 16; ++c4) {
                    float4 l = *(const float4*)&Lr[c4*4];
                    int cb = 64*k + c4*4;
                    s1 += l.x*rb[cb] + l.y*rb[cb+1] + l.z*rb[cb+2] + l.w*rb[cb+3];
                    s2 += l.x*ro[cb] + l.y*ro[cb+1] + l.z*ro[cb+2] + l.w*ro[cb+3];
                }
                rb[mm] -= s1; ro[mm] -= s2;
            }
            __syncthreads();
        }
        for (int k = 7; k >= 0; --k) {         // backward
            if (tid < 64) {
                const float* D0 = Dinvs + k*4096;
                float s1 = 0.f, s2 = 0.f;
                for (int c = 0; c < 64; ++c) {
                    float w = D0[c*64 + tid];
                    s1 += w*rb[64*k+c]; s2 += w*ro[64*k+c];
                }
                xb[64*k+tid] = s1; xo[64*k+tid] = s2;
            }
            __syncthreads();
            for (int mm = tid; mm < 64*k; mm += 512) {
                const float* Ur = LmatT + (size_t)mm*512 + 64*k;
                float s1 = 0.f, s2 = 0.f;
                for (int c4 = 0; c4 < 16; ++c4) {
                    float4 u = *(const float4*)&Ur[c4*4];
                    int cb = 64*k + c4*4;
                    s1 += u.x*xb[cb] + u.y*xb[cb+1] + u.z*xb[cb+2] + u.w*xb[cb+3];
                    s2 += u.x*xo[cb] + u.y*xo[cb+1] + u.z*xo[cb+2] + u.w*xo[cb+3];
                }
                rb[mm] -= s1; ro[mm] -= s2;
            }
            __syncthreads();
        }
        float pn = 0.f, pd = 0.f;
        for (int i = tid; i < 512; i += 512) { pn += xo[i]*bvs[i]; pd += xo[i]; }
        #pragma unroll
        for (int off = 32; off; off >>= 1) { pn += __shfl_down(pn, off); pd += __shfl_down(pd, off); }
        if ((tid & 63) == 0) { red[tid >> 6] = pn; red[8 + (tid >> 6)] = pd; }
        __syncthreads();
        if (tid == 0) {
            float sn = 0.f, sd = 0.f;
            #pragma unroll
            for (int i = 0; i < 8; ++i) { sn += red[i]; sd += red[8+i]; }
            red[16] = sn / sd;
        }
        __syncthreads();
        float ratio = red[16];
        for (int i = tid; i < 512; i += 512) out[i] = xb[i] - xo[i]*ratio;
    }
}

extern "C" void kernel_launch(void* const* d_in, const int* in_sizes, int n_in,
                              void* d_out, int out_size, void* d_ws, size_t ws_size,
                              hipStream_t stream) {
    (void)in_sizes; (void)n_in; (void)out_size;
    const float* pos  = (const float*)d_in[0];
    const float* qv   = (const float*)d_in[1];
    const float* cell = (const float*)d_in[2];
    float* out = (float*)d_out;
    char* ws = (char*)d_ws;
    size_t off = 0;
    auto alloc = [&](size_t bytes) -> void* {
        void* p = (void*)(ws + off);
        off = (off + bytes + 255) & ~(size_t)255;
        return p;
    };
    float4* kdata = (float4*)alloc((size_t)KPAD*16);
    float4* uq    = (float4*)alloc((size_t)N_ATOMS*16);
    float*  Scw   = (float*)alloc((size_t)KPAD*4);
    float*  Ssw   = (float*)alloc((size_t)KPAD*4);
    float*  Bvec  = (float*)alloc(512*4);
    float*  Amat  = (float*)alloc((size_t)512*512*4);
    float*  LmatT = (float*)alloc((size_t)512*512*4);
    float*  Dinvs = (float*)alloc((size_t)8*4096*4);
    // SL must divide 288 (KSL multiple of 32)
    static const int slopts[10] = {96, 72, 48, 36, 24, 16, 12, 8, 4, 1};
    int SL = 1;
    for (int ci = 0; ci < 10; ++ci) {
        size_t need = (size_t)10 * slopts[ci] * 16384 * 4;
        if (off + need <= ws_size) { SL = slopts[ci]; break; }
    }
    float* partial = (float*)alloc((size_t)10*SL*16384*4);
    const int KSL = KPAD / SL;
    const int nsyrk = 10*SL;

    prep<<<dim3(44), dim3(256), 0, stream>>>(pos, qv, cell, kdata, uq, out);
    syrk_sf<<<dim3(nsyrk + 144), dim3(256), 0, stream>>>(kdata, uq, partial,
                                                         Scw, Ssw, SL, KSL, nsyrk);
    redfield<<<dim3(640), dim3(256), 0, stream>>>(partial, cell, Amat, kdata, uq,
                                                  Scw, Ssw, Bvec, SL);
    chol_solve<<<dim3(1), dim3(512), 0, stream>>>(Amat, LmatT, Dinvs, Bvec, out);
}

// Round 11
// 589.673 us; speedup vs baseline: 1.6596x; 1.6596x over previous
//
#include <hip/hip_runtime.h>
#include <math.h>

#define N_ATOMS 2048
#define NM      512
#define KHALF   9040          // half k-grid (k=0 excluded; pairs folded into wk^2=2*kfac)
#define KPAD    9216          // padded, wk=0 on pads
#define TWO_PI  6.2831853071795864769f
#define SIGMA   0.5540037f
#define FOUR_PI 12.566370614359172954f

__device__ inline void inv3x3(const float* __restrict__ c, float inv[3][3], float& det) {
    float a00=c[0],a01=c[1],a02=c[2],a10=c[3],a11=c[4],a12=c[5],a20=c[6],a21=c[7],a22=c[8];
    float c00 =  a11*a22 - a12*a21;
    float c01 = -(a10*a22 - a12*a20);
    float c02 =  a10*a21 - a11*a20;
    det = a00*c00 + a01*c01 + a02*c02;
    float id = 1.0f/det;
    inv[0][0] = c00*id;
    inv[0][1] = -(a01*a22 - a02*a21)*id;
    inv[0][2] =  (a01*a12 - a02*a11)*id;
    inv[1][0] = c01*id;
    inv[1][1] =  (a00*a22 - a02*a20)*id;
    inv[1][2] = -(a00*a12 - a02*a10)*id;
    inv[2][0] = c02*id;
    inv[2][1] = -(a00*a21 - a01*a20)*id;
    inv[2][2] =  (a00*a11 - a01*a10)*id;
}

// Fast grid barrier (R6-proven): arrive on cnt, last arriver releases flag,
// spinners poll with relaxed agent loads + s_sleep. Requires all blocks resident.
__device__ __forceinline__ void gbar(int* cnt, int* flag, int ph, int G) {
    __syncthreads();
    if (threadIdx.x == 0) {
        __threadfence();
        int prev = __hip_atomic_fetch_add(cnt, 1, __ATOMIC_ACQ_REL, __HIP_MEMORY_SCOPE_AGENT);
        if (prev == G*ph - 1) {
            __hip_atomic_store(flag, ph, __ATOMIC_RELEASE, __HIP_MEMORY_SCOPE_AGENT);
        } else {
            while (__hip_atomic_load(flag, __ATOMIC_RELAXED, __HIP_MEMORY_SCOPE_AGENT) < ph)
                __builtin_amdgcn_s_sleep(4);
        }
        __threadfence();
    }
    __syncthreads();
}

// ---------------- kernel 1: k-grid + atom prep ----------------
__global__ void prep(const float* __restrict__ pos, const float* __restrict__ qv,
                     const float* __restrict__ cell, float4* __restrict__ kdata,
                     float4* __restrict__ uq, float* __restrict__ out) {
    const int bb = blockIdx.x, tid = threadIdx.x;
    if (bb < 36) {
        int t = bb*256 + tid;
        float gx=0.f, gy=0.f, gz=0.f, wk=0.f;
        if (t < KHALF) {
            int iz = t % 41; int rem = t / 41; int iy = rem % 21; int ix = rem / 21;
            gx = (float)(ix - 10); gy = (float)(iy - 10); gz = (float)(iz - 20);
            float inv[3][3], det;
            inv3x3(cell, inv, det);
            float kx = TWO_PI*(gx*inv[0][0] + gy*inv[0][1] + gz*inv[0][2]);
            float ky = TWO_PI*(gx*inv[1][0] + gy*inv[1][1] + gz*inv[1][2]);
            float kz = TWO_PI*(gx*inv[2][0] + gy*inv[2][1] + gz*inv[2][2]);
            float k2 = kx*kx + ky*ky + kz*kz;
            float kfac = __expf(-0.5f*SIGMA*SIGMA*k2) / k2;
            wk = sqrtf(2.0f*kfac);
        }
        kdata[t] = make_float4(gx, gy, gz, wk);
    } else {
        int i = (bb-36)*256 + tid;
        float inv[3][3], det;
        inv3x3(cell, inv, det);
        float x = pos[3*i], y = pos[3*i+1], z = pos[3*i+2];
        float u = x*inv[0][0] + y*inv[1][0] + z*inv[2][0];
        float v = x*inv[0][1] + y*inv[1][1] + z*inv[2][1];
        float w = x*inv[0][2] + y*inv[1][2] + z*inv[2][2];
        float qi = qv[i];
        uq[i] = make_float4(u, v, w, qi);
        if (i >= NM) out[i] = qi;
        if (i == 0) { out[N_ATOMS] = 0.f; out[N_ATOMS+1] = 0.f; }
    }
}

// ---------------- kernel 2: split-K SYRK + structf (folded) ----------------
__global__ void __launch_bounds__(256, 2) syrk_sf(const float4* __restrict__ kdata,
        const float4* __restrict__ uq, float* __restrict__ partial,
        float* __restrict__ Scw, float* __restrict__ Ssw, int SL, int KSL, int nsyrk) {
    __shared__ float smem[16384];
    const int tid = threadIdx.x;
    if ((int)blockIdx.x >= nsyrk) {
        int ch = blockIdx.x - nsyrk;          // 0..143
        int kk = tid & 63, sp = tid >> 6;
        int k = ch*64 + kk;
        float4 kd = kdata[k];
        float sc = 0.f, ss = 0.f;
        int jlo = NM + sp*384, jhi = jlo + 384;
        for (int j = jlo; j < jhi; ++j) {
            float4 at = uq[j];
            float ph = TWO_PI*(kd.x*at.x + kd.y*at.y + kd.z*at.z);
            float s, c; __sincosf(ph, &s, &c);
            sc += at.w * c;
            ss += at.w * s;
        }
        smem[sp*64 + kk] = sc;
        smem[256 + sp*64 + kk] = ss;
        __syncthreads();
        if (sp == 0) {
            float c = smem[kk] + smem[64+kk] + smem[128+kk] + smem[192+kk];
            float s = smem[256+kk] + smem[320+kk] + smem[384+kk] + smem[448+kk];
            float kf2 = kd.w * kd.w;
            Scw[k] = kf2 * c;
            Ssw[k] = kf2 * s;
        }
        return;
    }
    int s = blockIdx.x % SL;
    int t = blockIdx.x / SL;
    int rt = 0;
    while ((rt+1)*(rt+2)/2 <= t) ++rt;
    int ct = t - rt*(rt+1)/2;
    const int row0 = rt << 7, c0 = ct << 7;
    const bool diag = (row0 == c0);
    float* crT = smem; float* srT = smem+4096; float* ccT = smem+8192; float* scT = smem+12288;
    const float* ccR = diag ? crT : ccT;   // diagonal tiles: col phases == row phases
    const float* scR = diag ? srT : scT;
    const int i0 = (tid & 15) << 3;
    const int j0 = (tid >> 4) << 3;
    float acc[8][8];
    #pragma unroll
    for (int i = 0; i < 8; ++i)
        #pragma unroll
        for (int j = 0; j < 8; ++j) acc[i][j] = 0.f;
    const int k0 = s * KSL;
    const int nch = KSL >> 5;
    for (int ch = 0; ch < nch; ++ch) {
        int kc = k0 + (ch << 5);
        __syncthreads();
        #pragma unroll
        for (int w = 0; w < 16; ++w) {
            int job = tid + (w << 8);
            int kk = job >> 7, a = job & 127;
            float4 kd = kdata[kc + kk];
            float4 at = uq[row0 + a];
            float ph = TWO_PI*(kd.x*at.x + kd.y*at.y + kd.z*at.z);
            float sn, cs;
            __sincosf(ph, &sn, &cs);
            crT[kk*128+a] = kd.w * cs;
            srT[kk*128+a] = kd.w * sn;
        }
        if (!diag) {
            #pragma unroll
            for (int w = 0; w < 16; ++w) {
                int job = tid + (w << 8);
                int kk = job >> 7, a = job & 127;
                float4 kd = kdata[kc + kk];
                float4 at = uq[c0 + a];
                float ph = TWO_PI*(kd.x*at.x + kd.y*at.y + kd.z*at.z);
                float sn, cs;
                __sincosf(ph, &sn, &cs);
                ccT[kk*128+a] = kd.w * cs;
                scT[kk*128+a] = kd.w * sn;
            }
        }
        __syncthreads();
        #pragma unroll 4
        for (int kk = 0; kk < 32; ++kk) {
            float cr[8], sr[8], cc[8], sv[8];
            *(float4*)&cr[0] = *(const float4*)&crT[kk*128+i0];
            *(float4*)&cr[4] = *(const float4*)&crT[kk*128+i0+4];
            *(float4*)&sr[0] = *(const float4*)&srT[kk*128+i0];
            *(float4*)&sr[4] = *(const float4*)&srT[kk*128+i0+4];
            *(float4*)&cc[0] = *(const float4*)&ccR[kk*128+j0];
            *(float4*)&cc[4] = *(const float4*)&ccR[kk*128+j0+4];
            *(float4*)&sv[0] = *(const float4*)&scR[kk*128+j0];
            *(float4*)&sv[4] = *(const float4*)&scR[kk*128+j0+4];
            #pragma unroll
            for (int i = 0; i < 8; ++i)
                #pragma unroll
                for (int j = 0; j < 8; ++j)
                    acc[i][j] += cr[i]*cc[j] + sr[i]*sv[j];
        }
    }
    float* P = partial + ((size_t)blockIdx.x << 14);
    #pragma unroll
    for (int i = 0; i < 8; ++i) {
        *(float4*)&P[(i0+i)*128 + j0]     = make_float4(acc[i][0], acc[i][1], acc[i][2], acc[i][3]);
        *(float4*)&P[(i0+i)*128 + j0 + 4] = make_float4(acc[i][4], acc[i][5], acc[i][6], acc[i][7]);
    }
}

// ---- pivot factor+inverse, OPTIMIZED: register-wave chol (wave 0) +
//      float4 c-vectorized recursive-doubling inverse. D,T ld=68; M >=1024 floats.
__device__ void diag_fast(float* D, float* T, float* M, int tid, int pd, float* Dinvs) {
    __syncthreads();
    if (tid < 64) {
        float row[64];
        #pragma unroll
        for (int c = 0; c < 64; ++c) row[c] = D[tid*68 + c];
        #pragma unroll
        for (int j = 0; j < 64; ++j) {
            float pj = __shfl(row[j], j);
            float rinv = 1.0f / sqrtf(pj);
            float lj = row[j] * rinv;     // r>=j: L[r][j]; lane j gets sqrt(pj)
            row[j] = lj;
            #pragma unroll
            for (int c = j+1; c < 64; ++c) {
                float lcj = __shfl(lj, c);
                row[c] = fmaf(-lj, lcj, row[c]);
            }
        }
        #pragma unroll
        for (int c = 0; c < 64; ++c) D[tid*68 + c] = row[c];   // lower valid
    }
    __syncthreads();
    for (int idx = tid; idx < 64*68; idx += 256) T[idx] = 0.f;
    __syncthreads();
    if (tid < 64) {   // 8x8 diag-block inverses (lower-tri)
        int s = tid >> 3, c = tid & 7, o = s*8;
        float x[8];
        #pragma unroll
        for (int r = 0; r < 8; ++r) {
            float acc = (r == c) ? 1.0f : 0.0f;
            #pragma unroll
            for (int j = 0; j < 8; ++j)
                if (j < r) acc -= D[(o+r)*68 + o + j] * x[j];
            x[r] = (r >= c) ? acc / D[(o+r)*68 + o + r] : 0.0f;
        }
        #pragma unroll
        for (int r = 0; r < 8; ++r)
            if (r >= c) T[(o+r)*68 + o + c] = x[r];
    }
    __syncthreads();
    // doubling levels, float4-vectorized over output columns
    #pragma unroll
    for (int lvl = 0; lvl < 3; ++lvl) {
        const int h = 8 << lvl, pairs = 4 >> lvl;
        const int hq = h >> 2, nq = pairs * h * hq;
        for (int e = tid; e < nq; e += 256) {   // M = L21 * W11
            int pr = e / (h*hq); int rem = e - pr*h*hq;
            int r2 = rem / hq, cq = rem - (rem/hq)*hq;
            int o = pr*2*h;
            float4 acc = make_float4(0.f, 0.f, 0.f, 0.f);
            for (int j2 = cq*4; j2 < h; ++j2) {    // W11 zero above diag
                float l = D[(o+h+r2)*68 + o + j2];
                float4 w = *(const float4*)&T[(o+j2)*68 + o + cq*4];
                acc.x += l*w.x; acc.y += l*w.y; acc.z += l*w.z; acc.w += l*w.w;
            }
            *(float4*)&M[(pr*h + r2)*h + cq*4] = acc;
        }
        __syncthreads();
        for (int e = tid; e < nq; e += 256) {   // W21 = -W22 * M
            int pr = e / (h*hq); int rem = e - pr*h*hq;
            int r2 = rem / hq, cq = rem - (rem/hq)*hq;
            int o = pr*2*h;
            float4 acc = make_float4(0.f, 0.f, 0.f, 0.f);
            for (int j2 = 0; j2 <= r2; ++j2) {     // W22 lower-tri
                float w = T[(o+h+r2)*68 + o+h + j2];
                float4 m = *(const float4*)&M[(pr*h + j2)*h + cq*4];
                acc.x += w*m.x; acc.y += w*m.y; acc.z += w*m.z; acc.w += w*m.w;
            }
            float4 st = make_float4(-acc.x, -acc.y, -acc.z, -acc.w);
            *(float4*)&T[(o+h+r2)*68 + o + cq*4] = st;
        }
        __syncthreads();
    }
    for (int idx = tid; idx < 4096; idx += 256) {
        int r = idx >> 6, c = idx & 63;
        Dinvs[pd*4096 + idx] = (c <= r) ? T[r*68+c] : 0.f;
    }
}

// ---------------- kernel 3: reduceA + field ----------------
__global__ void __launch_bounds__(256) redfield(const float* __restrict__ partial,
        const float* __restrict__ cell, float* __restrict__ Amat,
        const float4* __restrict__ kdata, const float4* __restrict__ uq,
        const float* __restrict__ Scw, const float* __restrict__ Ssw,
        float* __restrict__ Bvec, int SL) {
    const int b = blockIdx.x, tid = threadIdx.x;
    float inv[3][3], det;
    inv3x3(cell, inv, det);
    const float scal = FOUR_PI / fabsf(det);
    if (b < 512) {
        for (int idx = b*256 + tid; idx < 512*512; idx += 512*256) {
            int i = idx >> 9, j = idx & 511;
            if (i < j) continue;
            int rt2 = i >> 7, ct2 = j >> 7;
            int t2 = rt2*(rt2+1)/2 + ct2;
            const float* p = partial + ((size_t)(t2*SL) << 14) + ((i & 127) << 7) + (j & 127);
            float a0=0.f,a1=0.f,a2=0.f,a3=0.f,a4=0.f,a5=0.f,a6=0.f,a7=0.f;
            int s = 0;
            for (; s + 8 <= SL; s += 8) {
                a0 += p[(size_t)(s+0) << 14];
                a1 += p[(size_t)(s+1) << 14];
                a2 += p[(size_t)(s+2) << 14];
                a3 += p[(size_t)(s+3) << 14];
                a4 += p[(size_t)(s+4) << 14];
                a5 += p[(size_t)(s+5) << 14];
                a6 += p[(size_t)(s+6) << 14];
                a7 += p[(size_t)(s+7) << 14];
            }
            for (; s < SL; ++s) a0 += p[(size_t)s << 14];
            float sum = ((a0+a1)+(a2+a3)) + ((a4+a5)+(a6+a7));
            float v = scal * sum;
            Amat[(size_t)i*512 + j] = v;
            Amat[(size_t)j*512 + i] = v;
        }
    } else {
        int ch = b - 512;
        int atom = ch*4 + (tid >> 6);
        int lane = tid & 63;
        float4 at = uq[atom];
        float acc = 0.f;
        for (int k = lane; k < KPAD; k += 64) {
            float4 kd = kdata[k];
            float ph = TWO_PI*(kd.x*at.x + kd.y*at.y + kd.z*at.z);
            float s, c; __sincosf(ph, &s, &c);
            acc += c*Scw[k] + s*Ssw[k];
        }
        #pragma unroll
        for (int off = 32; off; off >>= 1) acc += __shfl_down(acc, off);
        if (lane == 0) Bvec[atom] = -scal * acc;
    }
}

// ---------------- kernel 4: persistent tail (diag0 + 7 chol phases + solve) ----------------
__global__ void __launch_bounds__(256) tail_persist(float* __restrict__ Amat,
        float* __restrict__ Lmat, float* __restrict__ LmatT, float* __restrict__ Dinvs,
        const float* __restrict__ Bvec, float* __restrict__ out,
        int* cnt, int* flag) {
    __shared__ float smem[15360];   // 60 KB
    const int b = blockIdx.x, tid = threadIdx.x;
    const int G = 28;

    // ---- phase: diag0 (block 0) ----
    if (b == 0) {
        float* D = smem; float* T = smem + 4352; float* M = smem + 8704;
        for (int idx = tid; idx < 4096; idx += 256) {
            int r = idx >> 6, c = idx & 63;
            D[r*68+c] = Amat[(size_t)r*512 + c];
        }
        diag_fast(D, T, M, tid, 0, Dinvs);
    }
    gbar(cnt, flag, 1, G);

    // ---- Cholesky steps p=0..6 ----
    for (int p = 0; p <= 6; ++p) {
        const int T7 = 7 - p, ntile = T7*(T7+1)/2;
        if (b < ntile) {
            const int tt = b;
            int rt = 0; while ((rt+1)*(rt+2)/2 <= tt) ++rt;
            const int ct = tt - rt*(rt+1)/2;
            const int R = p + 1 + rt, C = p + 1 + ct;
            float* ArT = smem;            // [64][68]
            float* DvT = smem + 4352;     // [64][68]
            float* LrT = smem + 8704;     // [64][68]
            float* LcT = smem + 13056;    // [64][36]
            float pref[16];
            if (R != C) {
                #pragma unroll
                for (int w = 0; w < 16; ++w) {
                    int idx = tid + (w << 8);
                    pref[w] = Amat[(size_t)(C*64 + (idx >> 6))*512 + p*64 + (idx & 63)];
                }
            }
            __syncthreads();              // guard smem reuse across phases
            for (int idx = tid; idx < 4096; idx += 256) {
                int j = idx >> 6, d = idx & 63;
                DvT[d*68 + j] = Dinvs[p*4096 + j*64 + d];
            }
            for (int idx = tid; idx < 4096; idx += 256) {
                int i = idx >> 6, k = idx & 63;
                ArT[k*68 + i] = Amat[(size_t)(R*64 + i)*512 + p*64 + k];
            }
            __syncthreads();
            const int i0 = (tid & 15)*4, j0 = (tid >> 4)*4;
            float lr[4][4];
            #pragma unroll
            for (int ii = 0; ii < 4; ++ii)
                #pragma unroll
                for (int jj = 0; jj < 4; ++jj) lr[ii][jj] = 0.f;
            for (int k = 0; k < 64; ++k) {     // Lr = A21r * Dinv^T
                float4 av = *(float4*)&ArT[k*68 + i0];
                float4 dv = *(float4*)&DvT[k*68 + j0];
                lr[0][0] += av.x*dv.x; lr[0][1] += av.x*dv.y; lr[0][2] += av.x*dv.z; lr[0][3] += av.x*dv.w;
                lr[1][0] += av.y*dv.x; lr[1][1] += av.y*dv.y; lr[1][2] += av.y*dv.z; lr[1][3] += av.y*dv.w;
                lr[2][0] += av.z*dv.x; lr[2][1] += av.z*dv.y; lr[2][2] += av.z*dv.z; lr[2][3] += av.z*dv.w;
                lr[3][0] += av.w*dv.x; lr[3][1] += av.w*dv.y; lr[3][2] += av.w*dv.z; lr[3][3] += av.w*dv.w;
            }
            #pragma unroll
            for (int ii = 0; ii < 4; ++ii)
                #pragma unroll
                for (int jj = 0; jj < 4; ++jj)
                    LrT[(j0+jj)*68 + i0+ii] = lr[ii][jj];
            __syncthreads();
            if (C == p + 1) {   // write panel column of L (+ transpose)
                for (int idx = tid; idx < 4096; idx += 256) {
                    int i2 = idx >> 6, c2 = idx & 63;
                    Lmat[(size_t)(R*64+i2)*512 + p*64 + c2] = LrT[c2*68 + i2];
                }
                for (int idx = tid; idx < 4096; idx += 256) {
                    int c2 = idx >> 6, i2 = idx & 63;
                    LmatT[(size_t)(p*64+c2)*512 + R*64 + i2] = LrT[c2*68 + i2];
                }
            }
            if (R == C) {
                float up[4][4];
                #pragma unroll
                for (int ii = 0; ii < 4; ++ii)
                    #pragma unroll
                    for (int jj = 0; jj < 4; ++jj) up[ii][jj] = 0.f;
                for (int k = 0; k < 64; ++k) {
                    float4 av = *(float4*)&LrT[k*68 + i0];
                    float4 bv = *(float4*)&LrT[k*68 + j0];
                    up[0][0] += av.x*bv.x; up[0][1] += av.x*bv.y; up[0][2] += av.x*bv.z; up[0][3] += av.x*bv.w;
                    up[1][0] += av.y*bv.x; up[1][1] += av.y*bv.y; up[1][2] += av.y*bv.z; up[1][3] += av.y*bv.w;
                    up[2][0] += av.z*bv.x; up[2][1] += av.z*bv.y; up[2][2] += av.z*bv.z; up[2][3] += av.z*bv.w;
                    up[3][0] += av.w*bv.x; up[3][1] += av.w*bv.y; up[3][2] += av.w*bv.z; up[3][3] += av.w*bv.w;
                }
                float vals[4][4];
                #pragma unroll
                for (int ii = 0; ii < 4; ++ii)
                    #pragma unroll
                    for (int jj = 0; jj < 4; ++jj) {
                        size_t gix = (size_t)(R*64+i0+ii)*512 + C*64 + j0 + jj;
                        float v = Amat[gix] - up[ii][jj];
                        Amat[gix] = v;
                        vals[ii][jj] = v;
                    }
                if (tt == 0) {   // factor + invert next pivot
                    float* D = smem; float* T = smem + 4352; float* M = smem + 8704;
                    __syncthreads();
                    #pragma unroll
                    for (int ii = 0; ii < 4; ++ii)
                        #pragma unroll
                        for (int jj = 0; jj < 4; ++jj)
                            D[(i0+ii)*68 + j0+jj] = vals[ii][jj];
                    diag_fast(D, T, M, tid, p+1, Dinvs);
                }
            } else {
                for (int w = 0; w < 16; ++w) {   // restage A21c from prefetched regs
                    int idx = tid + (w << 8);
                    ArT[(idx & 63)*68 + (idx >> 6)] = pref[w];
                }
                __syncthreads();
                const int c0l = (tid & 15)*4, jr0 = (tid >> 4)*2;
                #pragma unroll
                for (int hh = 0; hh < 2; ++hh) {
                    float lc[4][2];
                    #pragma unroll
                    for (int cc = 0; cc < 4; ++cc) { lc[cc][0] = 0.f; lc[cc][1] = 0.f; }
                    for (int d = 0; d < 64; ++d) {
                        float4 dv = *(float4*)&DvT[d*68 + c0l];
                        float2 av = *(float2*)&ArT[d*68 + hh*32 + jr0];
                        lc[0][0] += dv.x*av.x; lc[0][1] += dv.x*av.y;
                        lc[1][0] += dv.y*av.x; lc[1][1] += dv.y*av.y;
                        lc[2][0] += dv.z*av.x; lc[2][1] += dv.z*av.y;
                        lc[3][0] += dv.w*av.x; lc[3][1] += dv.w*av.y;
                    }
                    __syncthreads();
                    #pragma unroll
                    for (int cc = 0; cc < 4; ++cc) {
                        LcT[(c0l+cc)*36 + jr0]     = lc[cc][0];
                        LcT[(c0l+cc)*36 + jr0 + 1] = lc[cc][1];
                    }
                    __syncthreads();
                    float up[4][2];
                    #pragma unroll
                    for (int ii = 0; ii < 4; ++ii) { up[ii][0] = 0.f; up[ii][1] = 0.f; }
                    for (int c2 = 0; c2 < 64; ++c2) {
                        float4 lv = *(float4*)&LrT[c2*68 + i0];
                        float2 cv = *(float2*)&LcT[c2*36 + jr0];
                        up[0][0] += lv.x*cv.x; up[0][1] += lv.x*cv.y;
                        up[1][0] += lv.y*cv.x; up[1][1] += lv.y*cv.y;
                        up[2][0] += lv.z*cv.x; up[2][1] += lv.z*cv.y;
                        up[3][0] += lv.w*cv.x; up[3][1] += lv.w*cv.y;
                    }
                    #pragma unroll
                    for (int ii = 0; ii < 4; ++ii)
                        #pragma unroll
                        for (int jr = 0; jr < 2; ++jr) {
                            size_t gix = (size_t)(R*64+i0+ii)*512 + C*64 + hh*32 + jr0 + jr;
                            Amat[gix] -= up[ii][jr];
                        }
                }
            }
        }
        gbar(cnt, flag, p + 2, G);
    }

    // ---- Solve: L z = [B,1]; L^T x = z; combine; out[0:512] (block 0 only) ----
    if (b == 0) {
        float* rb  = smem;
        float* ro  = smem + 512;
        float* xb  = smem + 1024;
        float* xo  = smem + 1536;
        float* bvs = smem + 2048;
        float* red = smem + 2560;
        __syncthreads();
        for (int i = tid; i < 512; i += 256) {
            float bv = Bvec[i];
            bvs[i] = bv; rb[i] = bv; ro[i] = 1.0f;
        }
        __syncthreads();
        for (int k = 0; k < 8; ++k) {          // forward
            if (tid < 64) {
                const float* Dk = Dinvs + k*4096 + tid*64;
                float s1 = 0.f, s2 = 0.f;
                for (int c4 = 0; c4 < 16; ++c4) {
                    float4 w = *(const float4*)&Dk[c4*4];
                    int cb = 64*k + c4*4;
                    s1 += w.x*rb[cb] + w.y*rb[cb+1] + w.z*rb[cb+2] + w.w*rb[cb+3];
                    s2 += w.x*ro[cb] + w.y*ro[cb+1] + w.z*ro[cb+2] + w.w*ro[cb+3];
                }
                rb[64*k+tid] = s1; ro[64*k+tid] = s2;   // wave-lockstep
            }
            __syncthreads();
            for (int mm = 64*(k+1) + tid; mm < 512; mm += 256) {
                const float* Lr = Lmat + (size_t)mm*512 + 64*k;
                float s1 = 0.f, s2 = 0.f;
                for (int c4 = 0; c4 < 16; ++c4) {
                    float4 l = *(const float4*)&Lr[c4*4];
                    int cb = 64*k + c4*4;
                    s1 += l.x*rb[cb] + l.y*rb[cb+1] + l.z*rb[cb+2] + l.w*rb[cb+3];
                    s2 += l.x*ro[cb] + l.y*ro[cb+1] + l.z*ro[cb+2] + l.w*ro[cb+3];
                }
                rb[mm] -= s1; ro[mm] -= s2;
            }
            __syncthreads();
        }
        for (int k = 7; k >= 0; --k) {         // backward
            if (tid < 64) {
                const float* D0 = Dinvs + k*4096;
                float s1 = 0.f, s2 = 0.f;
                for (int c = 0; c < 64; ++c) {
                    float w = D0[c*64 + tid];
                    s1 += w*rb[64*k+c]; s2 += w*ro[64*k+c];
                }
                xb[64*k+tid] = s1; xo[64*k+tid] = s2;
            }
            __syncthreads();
            for (int mm = tid; mm < 64*k; mm += 256) {
                const float* Ur = LmatT + (size_t)mm*512 + 64*k;
                float s1 = 0.f, s2 = 0.f;
                for (int c4 = 0; c4 < 16; ++c4) {
                    float4 u = *(const float4*)&Ur[c4*4];
                    int cb = 64*k + c4*4;
                    s1 += u.x*xb[cb] + u.y*xb[cb+1] + u.z*xb[cb+2] + u.w*xb[cb+3];
                    s2 += u.x*xo[cb] + u.y*xo[cb+1] + u.z*xo[cb+2] + u.w*xo[cb+3];
                }
                rb[mm] -= s1; ro[mm] -= s2;
            }
            __syncthreads();
        }
        float pn = 0.f, pd = 0.f;
        for (int i = tid; i < 512; i += 256) { pn += xo[i]*bvs[i]; pd += xo[i]; }
        #pragma unroll
        for (int off = 32; off; off >>= 1) { pn += __shfl_down(pn, off); pd += __shfl_down(pd, off); }
        if ((tid & 63) == 0) { red[tid >> 6] = pn; red[4 + (tid >> 6)] = pd; }
        __syncthreads();
        if (tid == 0) {
            float sn = red[0]+red[1]+red[2]+red[3];
            float sd = red[4]+red[5]+red[6]+red[7];
            red[8] = sn / sd;
        }
        __syncthreads();
        float ratio = red[8];
        for (int i = tid; i < 512; i += 256) out[i] = xb[i] - xo[i]*ratio;
    }
}

extern "C" void kernel_launch(void* const* d_in, const int* in_sizes, int n_in,
                              void* d_out, int out_size, void* d_ws, size_t ws_size,
                              hipStream_t stream) {
    (void)in_sizes; (void)n_in; (void)out_size;
    const float* pos  = (const float*)d_in[0];
    const float* qv   = (const float*)d_in[1];
    const float* cell = (const float*)d_in[2];
    float* out = (float*)d_out;
    char* ws = (char*)d_ws;
    size_t off = 0;
    auto alloc = [&](size_t bytes) -> void* {
        void* p = (void*)(ws + off);
        off = (off + bytes + 255) & ~(size_t)255;
        return p;
    };
    float4* kdata = (float4*)alloc((size_t)KPAD*16);
    float4* uq    = (float4*)alloc((size_t)N_ATOMS*16);
    float*  Scw   = (float*)alloc((size_t)KPAD*4);
    float*  Ssw   = (float*)alloc((size_t)KPAD*4);
    float*  Bvec  = (float*)alloc(512*4);
    float*  Amat  = (float*)alloc((size_t)512*512*4);
    float*  Lmat  = (float*)alloc((size_t)512*512*4);
    float*  LmatT = (float*)alloc((size_t)512*512*4);
    float*  Dinvs = (float*)alloc((size_t)8*4096*4);
    int* bar = (int*)alloc(256);    // [0]=cnt, [1]=flag
    // SL must divide 288 (KSL multiple of 32)
    static const int slopts[10] = {96, 72, 48, 36, 24, 16, 12, 8, 4, 1};
    int SL = 1;
    for (int ci = 0; ci < 10; ++ci) {
        size_t need = (size_t)10 * slopts[ci] * 16384 * 4;
        if (off + need <= ws_size) { SL = slopts[ci]; break; }
    }
    float* partial = (float*)alloc((size_t)10*SL*16384*4);
    const int KSL = KPAD / SL;
    const int nsyrk = 10*SL;

    hipMemsetAsync(bar, 0, 8, stream);
    prep<<<dim3(44), dim3(256), 0, stream>>>(pos, qv, cell, kdata, uq, out);
    syrk_sf<<<dim3(nsyrk + 144), dim3(256), 0, stream>>>(kdata, uq, partial,
                                                         Scw, Ssw, SL, KSL, nsyrk);
    redfield<<<dim3(640), dim3(256), 0, stream>>>(partial, cell, Amat, kdata, uq,
                                                  Scw, Ssw, Bvec, SL);
    tail_persist<<<dim3(28), dim3(256), 0, stream>>>(Amat, Lmat, LmatT, Dinvs,
                                                     Bvec, out, bar, bar + 1);
}

// Round 12
// 537.475 us; speedup vs baseline: 1.8207x; 1.0971x over previous
//
#include <hip/hip_runtime.h>
#include <math.h>

#define N_ATOMS 2048
#define NM      512
#define KHALF   9040          // half k-grid (k=0 excluded; pairs folded into wk^2=2*kfac)
#define KPAD    9216          // padded, wk=0 on pads
#define TWO_PI  6.2831853071795864769f
#define SIGMA   0.5540037f
#define FOUR_PI 12.566370614359172954f

__device__ inline void inv3x3(const float* __restrict__ c, float inv[3][3], float& det) {
    float a00=c[0],a01=c[1],a02=c[2],a10=c[3],a11=c[4],a12=c[5],a20=c[6],a21=c[7],a22=c[8];
    float c00 =  a11*a22 - a12*a21;
    float c01 = -(a10*a22 - a12*a20);
    float c02 =  a10*a21 - a11*a20;
    det = a00*c00 + a01*c01 + a02*c02;
    float id = 1.0f/det;
    inv[0][0] = c00*id;
    inv[0][1] = -(a01*a22 - a02*a21)*id;
    inv[0][2] =  (a01*a12 - a02*a11)*id;
    inv[1][0] = c01*id;
    inv[1][1] =  (a00*a22 - a02*a20)*id;
    inv[1][2] = -(a00*a12 - a02*a10)*id;
    inv[2][0] = c02*id;
    inv[2][1] = -(a00*a21 - a01*a20)*id;
    inv[2][2] =  (a00*a11 - a01*a10)*id;
}

// Fence-light grid barrier: arrive = RELEASE fetch_add (1 wbl2); last arriver
// ACQUIRE-loads cnt (release-sequence -> hb from all arrivers) then RELEASE-stores
// flag; waiters spin relaxed then one ACQUIRE load (1 inv). No __threadfence.
__device__ __forceinline__ void gbar(int* cnt, int* flag, int ph, int G) {
    __syncthreads();
    if (threadIdx.x == 0) {
        int prev = __hip_atomic_fetch_add(cnt, 1, __ATOMIC_RELEASE, __HIP_MEMORY_SCOPE_AGENT);
        if (prev == G*ph - 1) {
            (void)__hip_atomic_load(cnt, __ATOMIC_ACQUIRE, __HIP_MEMORY_SCOPE_AGENT);
            __hip_atomic_store(flag, ph, __ATOMIC_RELEASE, __HIP_MEMORY_SCOPE_AGENT);
        } else {
            while (__hip_atomic_load(flag, __ATOMIC_RELAXED, __HIP_MEMORY_SCOPE_AGENT) < ph)
                __builtin_amdgcn_s_sleep(2);
            (void)__hip_atomic_load(flag, __ATOMIC_ACQUIRE, __HIP_MEMORY_SCOPE_AGENT);
        }
    }
    __syncthreads();
}

// ---------------- kernel 1: k-grid + atom prep ----------------
__global__ void prep(const float* __restrict__ pos, const float* __restrict__ qv,
                     const float* __restrict__ cell, float4* __restrict__ kdata,
                     float4* __restrict__ uq, float* __restrict__ out) {
    const int bb = blockIdx.x, tid = threadIdx.x;
    if (bb < 36) {
        int t = bb*256 + tid;
        float gx=0.f, gy=0.f, gz=0.f, wk=0.f;
        if (t < KHALF) {
            int iz = t % 41; int rem = t / 41; int iy = rem % 21; int ix = rem / 21;
            gx = (float)(ix - 10); gy = (float)(iy - 10); gz = (float)(iz - 20);
            float inv[3][3], det;
            inv3x3(cell, inv, det);
            float kx = TWO_PI*(gx*inv[0][0] + gy*inv[0][1] + gz*inv[0][2]);
            float ky = TWO_PI*(gx*inv[1][0] + gy*inv[1][1] + gz*inv[1][2]);
            float kz = TWO_PI*(gx*inv[2][0] + gy*inv[2][1] + gz*inv[2][2]);
            float k2 = kx*kx + ky*ky + kz*kz;
            float kfac = __expf(-0.5f*SIGMA*SIGMA*k2) / k2;
            wk = sqrtf(2.0f*kfac);
        }
        kdata[t] = make_float4(gx, gy, gz, wk);
    } else {
        int i = (bb-36)*256 + tid;
        float inv[3][3], det;
        inv3x3(cell, inv, det);
        float x = pos[3*i], y = pos[3*i+1], z = pos[3*i+2];
        float u = x*inv[0][0] + y*inv[1][0] + z*inv[2][0];
        float v = x*inv[0][1] + y*inv[1][1] + z*inv[2][1];
        float w = x*inv[0][2] + y*inv[1][2] + z*inv[2][2];
        float qi = qv[i];
        uq[i] = make_float4(u, v, w, qi);
        if (i >= NM) out[i] = qi;
        if (i == 0) { out[N_ATOMS] = 0.f; out[N_ATOMS+1] = 0.f; }
    }
}

// ---------------- kernel 2: split-K SYRK + structf (folded) ----------------
__global__ void __launch_bounds__(256, 2) syrk_sf(const float4* __restrict__ kdata,
        const float4* __restrict__ uq, float* __restrict__ partial,
        float* __restrict__ Scw, float* __restrict__ Ssw, int SL, int KSL, int nsyrk) {
    __shared__ float smem[16384];
    const int tid = threadIdx.x;
    if ((int)blockIdx.x >= nsyrk) {
        int ch = blockIdx.x - nsyrk;          // 0..143
        int kk = tid & 63, sp = tid >> 6;
        int k = ch*64 + kk;
        float4 kd = kdata[k];
        float sc = 0.f, ss = 0.f;
        int jlo = NM + sp*384, jhi = jlo + 384;
        for (int j = jlo; j < jhi; ++j) {
            float4 at = uq[j];
            float ph = TWO_PI*(kd.x*at.x + kd.y*at.y + kd.z*at.z);
            float s, c; __sincosf(ph, &s, &c);
            sc += at.w * c;
            ss += at.w * s;
        }
        smem[sp*64 + kk] = sc;
        smem[256 + sp*64 + kk] = ss;
        __syncthreads();
        if (sp == 0) {
            float c = smem[kk] + smem[64+kk] + smem[128+kk] + smem[192+kk];
            float s = smem[256+kk] + smem[320+kk] + smem[384+kk] + smem[448+kk];
            float kf2 = kd.w * kd.w;
            Scw[k] = kf2 * c;
            Ssw[k] = kf2 * s;
        }
        return;
    }
    int s = blockIdx.x % SL;
    int t = blockIdx.x / SL;
    int rt = 0;
    while ((rt+1)*(rt+2)/2 <= t) ++rt;
    int ct = t - rt*(rt+1)/2;
    const int row0 = rt << 7, c0 = ct << 7;
    const bool diag = (row0 == c0);
    float* crT = smem; float* srT = smem+4096; float* ccT = smem+8192; float* scT = smem+12288;
    const float* ccR = diag ? crT : ccT;   // diagonal tiles: col phases == row phases
    const float* scR = diag ? srT : scT;
    const int i0 = (tid & 15) << 3;
    const int j0 = (tid >> 4) << 3;
    float acc[8][8];
    #pragma unroll
    for (int i = 0; i < 8; ++i)
        #pragma unroll
        for (int j = 0; j < 8; ++j) acc[i][j] = 0.f;
    const int k0 = s * KSL;
    const int nch = KSL >> 5;
    for (int ch = 0; ch < nch; ++ch) {
        int kc = k0 + (ch << 5);
        __syncthreads();
        #pragma unroll
        for (int w = 0; w < 16; ++w) {
            int job = tid + (w << 8);
            int kk = job >> 7, a = job & 127;
            float4 kd = kdata[kc + kk];
            float4 at = uq[row0 + a];
            float ph = TWO_PI*(kd.x*at.x + kd.y*at.y + kd.z*at.z);
            float sn, cs;
            __sincosf(ph, &sn, &cs);
            crT[kk*128+a] = kd.w * cs;
            srT[kk*128+a] = kd.w * sn;
        }
        if (!diag) {
            #pragma unroll
            for (int w = 0; w < 16; ++w) {
                int job = tid + (w << 8);
                int kk = job >> 7, a = job & 127;
                float4 kd = kdata[kc + kk];
                float4 at = uq[c0 + a];
                float ph = TWO_PI*(kd.x*at.x + kd.y*at.y + kd.z*at.z);
                float sn, cs;
                __sincosf(ph, &sn, &cs);
                ccT[kk*128+a] = kd.w * cs;
                scT[kk*128+a] = kd.w * sn;
            }
        }
        __syncthreads();
        #pragma unroll 4
        for (int kk = 0; kk < 32; ++kk) {
            float cr[8], sr[8], cc[8], sv[8];
            *(float4*)&cr[0] = *(const float4*)&crT[kk*128+i0];
            *(float4*)&cr[4] = *(const float4*)&crT[kk*128+i0+4];
            *(float4*)&sr[0] = *(const float4*)&srT[kk*128+i0];
            *(float4*)&sr[4] = *(const float4*)&srT[kk*128+i0+4];
            *(float4*)&cc[0] = *(const float4*)&ccR[kk*128+j0];
            *(float4*)&cc[4] = *(const float4*)&ccR[kk*128+j0+4];
            *(float4*)&sv[0] = *(const float4*)&scR[kk*128+j0];
            *(float4*)&sv[4] = *(const float4*)&scR[kk*128+j0+4];
            #pragma unroll
            for (int i = 0; i < 8; ++i)
                #pragma unroll
                for (int j = 0; j < 8; ++j)
                    acc[i][j] += cr[i]*cc[j] + sr[i]*sv[j];
        }
    }
    float* P = partial + ((size_t)blockIdx.x << 14);
    #pragma unroll
    for (int i = 0; i < 8; ++i) {
        *(float4*)&P[(i0+i)*128 + j0]     = make_float4(acc[i][0], acc[i][1], acc[i][2], acc[i][3]);
        *(float4*)&P[(i0+i)*128 + j0 + 4] = make_float4(acc[i][4], acc[i][5], acc[i][6], acc[i][7]);
    }
}

// ---- pivot factor+inverse: register-wave chol (wave 0) + float4-vectorized
//      recursive-doubling inverse. D,T ld=68; M >=1024 floats. 256 threads.
__device__ void diag_fast(float* D, float* T, float* M, int tid, int pd, float* Dinvs) {
    __syncthreads();
    if (tid < 64) {
        float row[64];
        #pragma unroll
        for (int c = 0; c < 64; ++c) row[c] = D[tid*68 + c];
        #pragma unroll
        for (int j = 0; j < 64; ++j) {
            float pj = __shfl(row[j], j);
            float rinv = 1.0f / sqrtf(pj);
            float lj = row[j] * rinv;     // r>=j: L[r][j]; lane j gets sqrt(pj)
            row[j] = lj;
            #pragma unroll
            for (int c = j+1; c < 64; ++c) {
                float lcj = __shfl(lj, c);
                row[c] = fmaf(-lj, lcj, row[c]);
            }
        }
        #pragma unroll
        for (int c = 0; c < 64; ++c) D[tid*68 + c] = row[c];   // lower valid
    }
    __syncthreads();
    for (int idx = tid; idx < 64*68; idx += 256) T[idx] = 0.f;
    __syncthreads();
    if (tid < 64) {   // 8x8 diag-block inverses (lower-tri)
        int s = tid >> 3, c = tid & 7, o = s*8;
        float x[8];
        #pragma unroll
        for (int r = 0; r < 8; ++r) {
            float acc = (r == c) ? 1.0f : 0.0f;
            #pragma unroll
            for (int j = 0; j < 8; ++j)
                if (j < r) acc -= D[(o+r)*68 + o + j] * x[j];
            x[r] = (r >= c) ? acc / D[(o+r)*68 + o + r] : 0.0f;
        }
        #pragma unroll
        for (int r = 0; r < 8; ++r)
            if (r >= c) T[(o+r)*68 + o + c] = x[r];
    }
    __syncthreads();
    #pragma unroll
    for (int lvl = 0; lvl < 3; ++lvl) {
        const int h = 8 << lvl, pairs = 4 >> lvl;
        const int hq = h >> 2, nq = pairs * h * hq;
        for (int e = tid; e < nq; e += 256) {   // M = L21 * W11
            int pr = e / (h*hq); int rem = e - pr*h*hq;
            int r2 = rem / hq, cq = rem - (rem/hq)*hq;
            int o = pr*2*h;
            float4 acc = make_float4(0.f, 0.f, 0.f, 0.f);
            for (int j2 = cq*4; j2 < h; ++j2) {    // W11 zero above diag
                float l = D[(o+h+r2)*68 + o + j2];
                float4 w = *(const float4*)&T[(o+j2)*68 + o + cq*4];
                acc.x += l*w.x; acc.y += l*w.y; acc.z += l*w.z; acc.w += l*w.w;
            }
            *(float4*)&M[(pr*h + r2)*h + cq*4] = acc;
        }
        __syncthreads();
        for (int e = tid; e < nq; e += 256) {   // W21 = -W22 * M
            int pr = e / (h*hq); int rem = e - pr*h*hq;
            int r2 = rem / hq, cq = rem - (rem/hq)*hq;
            int o = pr*2*h;
            float4 acc = make_float4(0.f, 0.f, 0.f, 0.f);
            for (int j2 = 0; j2 <= r2; ++j2) {     // W22 lower-tri
                float w = T[(o+h+r2)*68 + o+h + j2];
                float4 m = *(const float4*)&M[(pr*h + j2)*h + cq*4];
                acc.x += w*m.x; acc.y += w*m.y; acc.z += w*m.z; acc.w += w*m.w;
            }
            float4 st = make_float4(-acc.x, -acc.y, -acc.z, -acc.w);
            *(float4*)&T[(o+h+r2)*68 + o + cq*4] = st;
        }
        __syncthreads();
    }
    for (int idx = tid; idx < 4096; idx += 256) {
        int r = idx >> 6, c = idx & 63;
        Dinvs[pd*4096 + idx] = (c <= r) ? T[r*68+c] : 0.f;
    }
}

// ---------------- kernel 3: reduceA + field ----------------
__global__ void __launch_bounds__(256) redfield(const float* __restrict__ partial,
        const float* __restrict__ cell, float* __restrict__ Amat,
        const float4* __restrict__ kdata, const float4* __restrict__ uq,
        const float* __restrict__ Scw, const float* __restrict__ Ssw,
        float* __restrict__ Bvec, int SL) {
    const int b = blockIdx.x, tid = threadIdx.x;
    float inv[3][3], det;
    inv3x3(cell, inv, det);
    const float scal = FOUR_PI / fabsf(det);
    if (b < 512) {
        for (int idx = b*256 + tid; idx < 512*512; idx += 512*256) {
            int i = idx >> 9, j = idx & 511;
            if (i < j) continue;
            int rt2 = i >> 7, ct2 = j >> 7;
            int t2 = rt2*(rt2+1)/2 + ct2;
            const float* p = partial + ((size_t)(t2*SL) << 14) + ((i & 127) << 7) + (j & 127);
            float a0=0.f,a1=0.f,a2=0.f,a3=0.f,a4=0.f,a5=0.f,a6=0.f,a7=0.f;
            int s = 0;
            for (; s + 8 <= SL; s += 8) {
                a0 += p[(size_t)(s+0) << 14];
                a1 += p[(size_t)(s+1) << 14];
                a2 += p[(size_t)(s+2) << 14];
                a3 += p[(size_t)(s+3) << 14];
                a4 += p[(size_t)(s+4) << 14];
                a5 += p[(size_t)(s+5) << 14];
                a6 += p[(size_t)(s+6) << 14];
                a7 += p[(size_t)(s+7) << 14];
            }
            for (; s < SL; ++s) a0 += p[(size_t)s << 14];
            float sum = ((a0+a1)+(a2+a3)) + ((a4+a5)+(a6+a7));
            float v = scal * sum;
            Amat[(size_t)i*512 + j] = v;
            Amat[(size_t)j*512 + i] = v;
        }
    } else {
        int ch = b - 512;
        int atom = ch*4 + (tid >> 6);
        int lane = tid & 63;
        float4 at = uq[atom];
        float acc = 0.f;
        for (int k = lane; k < KPAD; k += 64) {
            float4 kd = kdata[k];
            float ph = TWO_PI*(kd.x*at.x + kd.y*at.y + kd.z*at.z);
            float s, c; __sincosf(ph, &s, &c);
            acc += c*Scw[k] + s*Ssw[k];
        }
        #pragma unroll
        for (int off = 32; off; off >>= 1) acc += __shfl_down(acc, off);
        if (lane == 0) Bvec[atom] = -scal * acc;
    }
}

// ---------------- kernel 4: persistent chol (diag0 + 7 phases), 28 blocks ----------------
__global__ void __launch_bounds__(256) tail_chol(float* __restrict__ Amat,
        float* __restrict__ Lmat, float* __restrict__ LmatT, float* __restrict__ Dinvs,
        int* cnt, int* flag) {
    __shared__ float smem[15360];   // 60 KB
    const int b = blockIdx.x, tid = threadIdx.x;
    const int G = 28;

    // ---- phase: diag0 (block 0) ----
    if (b == 0) {
        float* D = smem; float* T = smem + 4352; float* M = smem + 8704;
        for (int idx = tid; idx < 4096; idx += 256) {
            int r = idx >> 6, c = idx & 63;
            D[r*68+c] = Amat[(size_t)r*512 + c];
        }
        diag_fast(D, T, M, tid, 0, Dinvs);
    }
    gbar(cnt, flag, 1, G);

    // ---- Cholesky steps p=0..6 ----
    for (int p = 0; p <= 6; ++p) {
        const int T7 = 7 - p, ntile = T7*(T7+1)/2;
        if (b < ntile) {
            const int tt = b;
            int rt = 0; while ((rt+1)*(rt+2)/2 <= tt) ++rt;
            const int ct = tt - rt*(rt+1)/2;
            const int R = p + 1 + rt, C = p + 1 + ct;
            float* ArT = smem;            // [64][68]
            float* DvT = smem + 4352;     // [64][68]
            float* LrT = smem + 8704;     // [64][68]
            float* LcT = smem + 13056;    // [64][36]
            float4 pref4[4];
            if (R != C) {
                #pragma unroll
                for (int w = 0; w < 4; ++w) {
                    int j = tid + (w << 8);
                    pref4[w] = *(const float4*)&Amat[(size_t)(C*64 + (j >> 4))*512 + p*64 + (j & 15)*4];
                }
            }
            __syncthreads();              // guard smem reuse across phases
            #pragma unroll
            for (int w = 0; w < 4; ++w) { // DvT[d][j] = Dinv[j][d]
                int t4 = tid + (w << 8);
                float4 v = *(const float4*)&Dinvs[p*4096 + t4*4];
                int j = t4 >> 4, d0 = (t4 & 15)*4;
                DvT[(d0+0)*68 + j] = v.x;
                DvT[(d0+1)*68 + j] = v.y;
                DvT[(d0+2)*68 + j] = v.z;
                DvT[(d0+3)*68 + j] = v.w;
            }
            #pragma unroll
            for (int w = 0; w < 4; ++w) { // ArT[k][i] = A[R*64+i][p*64+k]
                int j = tid + (w << 8);
                int i = j >> 4, k0 = (j & 15)*4;
                float4 v = *(const float4*)&Amat[(size_t)(R*64 + i)*512 + p*64 + k0];
                ArT[(k0+0)*68 + i] = v.x;
                ArT[(k0+1)*68 + i] = v.y;
                ArT[(k0+2)*68 + i] = v.z;
                ArT[(k0+3)*68 + i] = v.w;
            }
            __syncthreads();
            const int i0 = (tid & 15)*4, j0 = (tid >> 4)*4;
            float lr[4][4];
            #pragma unroll
            for (int ii = 0; ii < 4; ++ii)
                #pragma unroll
                for (int jj = 0; jj < 4; ++jj) lr[ii][jj] = 0.f;
            for (int k = 0; k < 64; ++k) {     // Lr = A21r * Dinv^T
                float4 av = *(float4*)&ArT[k*68 + i0];
                float4 dv = *(float4*)&DvT[k*68 + j0];
                lr[0][0] += av.x*dv.x; lr[0][1] += av.x*dv.y; lr[0][2] += av.x*dv.z; lr[0][3] += av.x*dv.w;
                lr[1][0] += av.y*dv.x; lr[1][1] += av.y*dv.y; lr[1][2] += av.y*dv.z; lr[1][3] += av.y*dv.w;
                lr[2][0] += av.z*dv.x; lr[2][1] += av.z*dv.y; lr[2][2] += av.z*dv.z; lr[2][3] += av.z*dv.w;
                lr[3][0] += av.w*dv.x; lr[3][1] += av.w*dv.y; lr[3][2] += av.w*dv.z; lr[3][3] += av.w*dv.w;
            }
            #pragma unroll
            for (int ii = 0; ii < 4; ++ii)
                #pragma unroll
                for (int jj = 0; jj < 4; ++jj)
                    LrT[(j0+jj)*68 + i0+ii] = lr[ii][jj];
            __syncthreads();
            if (C == p + 1) {   // write panel column of L (+ transpose)
                for (int idx = tid; idx < 4096; idx += 256) {
                    int i2 = idx >> 6, c2 = idx & 63;
                    Lmat[(size_t)(R*64+i2)*512 + p*64 + c2] = LrT[c2*68 + i2];
                }
                for (int idx = tid; idx < 4096; idx += 256) {
                    int c2 = idx >> 6, i2 = idx & 63;
                    LmatT[(size_t)(p*64+c2)*512 + R*64 + i2] = LrT[c2*68 + i2];
                }
            }
            if (R == C) {
                float up[4][4];
                #pragma unroll
                for (int ii = 0; ii < 4; ++ii)
                    #pragma unroll
                    for (int jj = 0; jj < 4; ++jj) up[ii][jj] = 0.f;
                for (int k = 0; k < 64; ++k) {
                    float4 av = *(float4*)&LrT[k*68 + i0];
                    float4 bv = *(float4*)&LrT[k*68 + j0];
                    up[0][0] += av.x*bv.x; up[0][1] += av.x*bv.y; up[0][2] += av.x*bv.z; up[0][3] += av.x*bv.w;
                    up[1][0] += av.y*bv.x; up[1][1] += av.y*bv.y; up[1][2] += av.y*bv.z; up[1][3] += av.y*bv.w;
                    up[2][0] += av.z*bv.x; up[2][1] += av.z*bv.y; up[2][2] += av.z*bv.z; up[2][3] += av.z*bv.w;
                    up[3][0] += av.w*bv.x; up[3][1] += av.w*bv.y; up[3][2] += av.w*bv.z; up[3][3] += av.w*bv.w;
                }
                float vals[4][4];
                #pragma unroll
                for (int ii = 0; ii < 4; ++ii)
                    #pragma unroll
                    for (int jj = 0; jj < 4; ++jj) {
                        size_t gix = (size_t)(R*64+i0+ii)*512 + C*64 + j0 + jj;
                        float v = Amat[gix] - up[ii][jj];
                        Amat[gix] = v;
                        vals[ii][jj] = v;
                    }
                if (tt == 0) {   // factor + invert next pivot
                    float* D = smem; float* T = smem + 4352; float* M = smem + 8704;
                    __syncthreads();
                    #pragma unroll
                    for (int ii = 0; ii < 4; ++ii)
                        #pragma unroll
                        for (int jj = 0; jj < 4; ++jj)
                            D[(i0+ii)*68 + j0+jj] = vals[ii][jj];
                    diag_fast(D, T, M, tid, p+1, Dinvs);
                }
            } else {
                #pragma unroll
                for (int w = 0; w < 4; ++w) {   // restage A21c from prefetched regs
                    int j = tid + (w << 8);
                    int i = j >> 4, k0 = (j & 15)*4;
                    ArT[(k0+0)*68 + i] = pref4[w].x;
                    ArT[(k0+1)*68 + i] = pref4[w].y;
                    ArT[(k0+2)*68 + i] = pref4[w].z;
                    ArT[(k0+3)*68 + i] = pref4[w].w;
                }
                __syncthreads();
                const int c0l = (tid & 15)*4, jr0 = (tid >> 4)*2;
                #pragma unroll
                for (int hh = 0; hh < 2; ++hh) {
                    float lc[4][2];
                    #pragma unroll
                    for (int cc = 0; cc < 4; ++cc) { lc[cc][0] = 0.f; lc[cc][1] = 0.f; }
                    for (int d = 0; d < 64; ++d) {
                        float4 dv = *(float4*)&DvT[d*68 + c0l];
                        float2 av = *(float2*)&ArT[d*68 + hh*32 + jr0];
                        lc[0][0] += dv.x*av.x; lc[0][1] += dv.x*av.y;
                        lc[1][0] += dv.y*av.x; lc[1][1] += dv.y*av.y;
                        lc[2][0] += dv.z*av.x; lc[2][1] += dv.z*av.y;
                        lc[3][0] += dv.w*av.x; lc[3][1] += dv.w*av.y;
                    }
                    __syncthreads();
                    #pragma unroll
                    for (int cc = 0; cc < 4; ++cc) {
                        LcT[(c0l+cc)*36 + jr0]     = lc[cc][0];
                        LcT[(c0l+cc)*36 + jr0 + 1] = lc[cc][1];
                    }
                    __syncthreads();
                    float up[4][2];
                    #pragma unroll
                    for (int ii = 0; ii < 4; ++ii) { up[ii][0] = 0.f; up[ii][1] = 0.f; }
                    for (int c2 = 0; c2 < 64; ++c2) {
                        float4 lv = *(float4*)&LrT[c2*68 + i0];
                        float2 cv = *(float2*)&LcT[c2*36 + jr0];
                        up[0][0] += lv.x*cv.x; up[0][1] += lv.x*cv.y;
                        up[1][0] += lv.y*cv.x; up[1][1] += lv.y*cv.y;
                        up[2][0] += lv.z*cv.x; up[2][1] += lv.z*cv.y;
                        up[3][0] += lv.w*cv.x; up[3][1] += lv.w*cv.y;
                    }
                    #pragma unroll
                    for (int ii = 0; ii < 4; ++ii)
                        #pragma unroll
                        for (int jr = 0; jr < 2; ++jr) {
                            size_t gix = (size_t)(R*64+i0+ii)*512 + C*64 + hh*32 + jr0 + jr;
                            Amat[gix] -= up[ii][jr];
                        }
                }
            }
        }
        if (p < 6) gbar(cnt, flag, p + 2, G);   // last phase synced by kernel boundary
    }
}

// ---------------- kernel 5: 2-RHS block substitution + combine (512 threads) ----------------
__global__ void __launch_bounds__(512) solve(const float* __restrict__ Lmat,
        const float* __restrict__ LmatT, const float* __restrict__ Dinvs,
        const float* __restrict__ Bvec, float* __restrict__ out) {
    __shared__ float smem[2592];
    float* rb  = smem;
    float* ro  = smem + 512;
    float* xb  = smem + 1024;
    float* xo  = smem + 1536;
    float* bvs = smem + 2048;
    float* red = smem + 2560;
    const int tid = threadIdx.x;
    if (tid < 512) {
        float bv = Bvec[tid];
        bvs[tid] = bv; rb[tid] = bv; ro[tid] = 1.0f;
    }
    __syncthreads();
    for (int k = 0; k < 8; ++k) {          // forward
        if (tid < 64) {
            const float* Dk = Dinvs + k*4096 + tid*64;
            float s1 = 0.f, s2 = 0.f;
            for (int c4 = 0; c4 < 16; ++c4) {
                float4 w = *(const float4*)&Dk[c4*4];
                int cb = 64*k + c4*4;
                s1 += w.x*rb[cb] + w.y*rb[cb+1] + w.z*rb[cb+2] + w.w*rb[cb+3];
                s2 += w.x*ro[cb] + w.y*ro[cb+1] + w.z*ro[cb+2] + w.w*ro[cb+3];
            }
            rb[64*k+tid] = s1; ro[64*k+tid] = s2;   // wave-lockstep
        }
        __syncthreads();
        for (int mm = 64*(k+1) + tid; mm < 512; mm += 512) {
            const float* Lr = Lmat + (size_t)mm*512 + 64*k;
            float s1 = 0.f, s2 = 0.f;
            for (int c4 = 0; c4 < 16; ++c4) {
                float4 l = *(const float4*)&Lr[c4*4];
                int cb = 64*k + c4*4;
                s1 += l.x*rb[cb] + l.y*rb[cb+1] + l.z*rb[cb+2] + l.w*rb[cb+3];
                s2 += l.x*ro[cb] + l.y*ro[cb+1] + l.z*ro[cb+2] + l.w*ro[cb+3];
            }
            rb[mm] -= s1; ro[mm] -= s2;
        }
        __syncthreads();
    }
    for (int k = 7; k >= 0; --k) {         // backward
        if (tid < 64) {
            const float* D0 = Dinvs + k*4096;
            float s1 = 0.f, s2 = 0.f;
            for (int c = 0; c < 64; ++c) {
                float w = D0[c*64 + tid];
                s1 += w*rb[64*k+c]; s2 += w*ro[64*k+c];
            }
            xb[64*k+tid] = s1; xo[64*k+tid] = s2;
        }
        __syncthreads();
        for (int mm = tid; mm < 64*k; mm += 512) {
            const float* Ur = LmatT + (size_t)mm*512 + 64*k;
            float s1 = 0.f, s2 = 0.f;
            for (int c4 = 0; c4 < 16; ++c4) {
                float4 u = *(const float4*)&Ur[c4*4];
                int cb = 64*k + c4*4;
                s1 += u.x*xb[cb] + u.y*xb[cb+1] + u.z*xb[cb+2] + u.w*xb[cb+3];
                s2 += u.x*xo[cb] + u.y*xo[cb+1] + u.z*xo[cb+2] + u.w*xo[cb+3];
            }
            rb[mm] -= s1; ro[mm] -= s2;
        }
        __syncthreads();
    }
    float pn = 0.f, pd = 0.f;
    if (tid < 512) { pn = xo[tid]*bvs[tid]; pd = xo[tid]; }
    #pragma unroll
    for (int off = 32; off; off >>= 1) { pn += __shfl_down(pn, off); pd += __shfl_down(pd, off); }
    if ((tid & 63) == 0) { red[tid >> 6] = pn; red[16 + (tid >> 6)] = pd; }
    __syncthreads();
    if (tid == 0) {
        float sn = 0.f, sd = 0.f;
        #pragma unroll
        for (int i = 0; i < 8; ++i) { sn += red[i]; sd += red[16+i]; }
        red[31] = sn / sd;
    }
    __syncthreads();
    float ratio = red[31];
    if (tid < 512) out[tid] = xb[tid] - xo[tid]*ratio;
}

extern "C" void kernel_launch(void* const* d_in, const int* in_sizes, int n_in,
                              void* d_out, int out_size, void* d_ws, size_t ws_size,
                              hipStream_t stream) {
    (void)in_sizes; (void)n_in; (void)out_size;
    const float* pos  = (const float*)d_in[0];
    const float* qv   = (const float*)d_in[1];
    const float* cell = (const float*)d_in[2];
    float* out = (float*)d_out;
    char* ws = (char*)d_ws;
    size_t off = 0;
    auto alloc = [&](size_t bytes) -> void* {
        void* p = (void*)(ws + off);
        off = (off + bytes + 255) & ~(size_t)255;
        return p;
    };
    float4* kdata = (float4*)alloc((size_t)KPAD*16);
    float4* uq    = (float4*)alloc((size_t)N_ATOMS*16);
    float*  Scw   = (float*)alloc((size_t)KPAD*4);
    float*  Ssw   = (float*)alloc((size_t)KPAD*4);
    float*  Bvec  = (float*)alloc(512*4);
    float*  Amat  = (float*)alloc((size_t)512*512*4);
    float*  Lmat  = (float*)alloc((size_t)512*512*4);
    float*  LmatT = (float*)alloc((size_t)512*512*4);
    float*  Dinvs = (float*)alloc((size_t)8*4096*4);
    int* bar = (int*)alloc(256);    // [0]=cnt, [1]=flag
    // SL must divide 288 (KSL multiple of 32)
    static const int slopts[10] = {96, 72, 48, 36, 24, 16, 12, 8, 4, 1};
    int SL = 1;
    for (int ci = 0; ci < 10; ++ci) {
        size_t need = (size_t)10 * slopts[ci] * 16384 * 4;
        if (off + need <= ws_size) { SL = slopts[ci]; break; }
    }
    float* partial = (float*)alloc((size_t)10*SL*16384*4);
    const int KSL = KPAD / SL;
    const int nsyrk = 10*SL;

    hipMemsetAsync(bar, 0, 8, stream);
    prep<<<dim3(44), dim3(256), 0, stream>>>(pos, qv, cell, kdata, uq, out);
    syrk_sf<<<dim3(nsyrk + 144), dim3(256), 0, stream>>>(kdata, uq, partial,
                                                         Scw, Ssw, SL, KSL, nsyrk);
    redfield<<<dim3(640), dim3(256), 0, stream>>>(partial, cell, Amat, kdata, uq,
                                                  Scw, Ssw, Bvec, SL);
    tail_chol<<<dim3(28), dim3(256), 0, stream>>>(Amat, Lmat, LmatT, Dinvs,
                                                  bar, bar + 1);
    solve<<<dim3(1), dim3(512), 0, stream>>>(Lmat, LmatT, Dinvs, Bvec, out);
}